// Round 16
// baseline (436.323 us; speedup 1.0000x reference)
//
#include <hip/hip_runtime.h>

#define NN 50000
#define EE 800000
#define FF 128
#define DD 64
#define GG 512

typedef unsigned short u16;

// ---------------- bf16 storage helpers (compute stays fp32) ----------------

__device__ __forceinline__ float bf2f(u16 h) {
    unsigned u = ((unsigned)h) << 16;
    return __builtin_bit_cast(float, u);
}
__device__ __forceinline__ u16 f2bf(float f) {
    unsigned u = __builtin_bit_cast(unsigned, f);
    u += 0x7fffu + ((u >> 16) & 1u);   // RNE
    return (u16)(u >> 16);
}
__device__ __forceinline__ float4 ldbf4(const u16* p) {
    uint2 v = *(const uint2*)p;
    float4 r;
    r.x = bf2f((u16)(v.x & 0xffffu)); r.y = bf2f((u16)(v.x >> 16));
    r.z = bf2f((u16)(v.y & 0xffffu)); r.w = bf2f((u16)(v.y >> 16));
    return r;
}
__device__ __forceinline__ void stbf4(u16* p, float4 v) {
    uint2 o;
    o.x = (unsigned)f2bf(v.x) | ((unsigned)f2bf(v.y) << 16);
    o.y = (unsigned)f2bf(v.z) | ((unsigned)f2bf(v.w) << 16);
    *(uint2*)p = o;
}
__device__ __forceinline__ void fma4(float4& a, const float4& w, float s) {
    a.x = fmaf(s, w.x, a.x); a.y = fmaf(s, w.y, a.y);
    a.z = fmaf(s, w.z, a.z); a.w = fmaf(s, w.w, a.w);
}
__device__ __forceinline__ void add4(float4& a, float4 b) {
    a.x += b.x; a.y += b.y; a.z += b.z; a.w += b.w;
}

// 8-wide unrolled neighbor gather: 8 independent loads in flight per group
__device__ __forceinline__ void gather16(float4& acc, const u16* __restrict__ in,
                                         const int* __restrict__ csr, int e0s, int e1s,
                                         int l16, int gbase) {
    for (int e0 = e0s; e0 < e1s; e0 += 16) {
        int cnt = min(16, e1s - e0);
        int srcv = (l16 < cnt) ? csr[e0 + l16] : 0;
        int j = 0;
        for (; j + 8 <= cnt; j += 8) {
            int i0 = __shfl(srcv, gbase + j);
            int i1 = __shfl(srcv, gbase + j + 1);
            int i2 = __shfl(srcv, gbase + j + 2);
            int i3 = __shfl(srcv, gbase + j + 3);
            int i4 = __shfl(srcv, gbase + j + 4);
            int i5 = __shfl(srcv, gbase + j + 5);
            int i6 = __shfl(srcv, gbase + j + 6);
            int i7 = __shfl(srcv, gbase + j + 7);
            float4 h0 = ldbf4(in + (size_t)i0 * 64 + l16 * 4);
            float4 h1 = ldbf4(in + (size_t)i1 * 64 + l16 * 4);
            float4 h2 = ldbf4(in + (size_t)i2 * 64 + l16 * 4);
            float4 h3 = ldbf4(in + (size_t)i3 * 64 + l16 * 4);
            float4 h4 = ldbf4(in + (size_t)i4 * 64 + l16 * 4);
            float4 h5 = ldbf4(in + (size_t)i5 * 64 + l16 * 4);
            float4 h6 = ldbf4(in + (size_t)i6 * 64 + l16 * 4);
            float4 h7 = ldbf4(in + (size_t)i7 * 64 + l16 * 4);
            add4(h0, h1); add4(h2, h3); add4(h4, h5); add4(h6, h7);
            add4(h0, h2); add4(h4, h6);
            add4(h0, h4);
            add4(acc, h0);
        }
        for (; j + 4 <= cnt; j += 4) {
            int i0 = __shfl(srcv, gbase + j);
            int i1 = __shfl(srcv, gbase + j + 1);
            int i2 = __shfl(srcv, gbase + j + 2);
            int i3 = __shfl(srcv, gbase + j + 3);
            float4 h0 = ldbf4(in + (size_t)i0 * 64 + l16 * 4);
            float4 h1 = ldbf4(in + (size_t)i1 * 64 + l16 * 4);
            float4 h2 = ldbf4(in + (size_t)i2 * 64 + l16 * 4);
            float4 h3 = ldbf4(in + (size_t)i3 * 64 + l16 * 4);
            add4(h0, h1); add4(h2, h3); add4(h0, h2);
            add4(acc, h0);
        }
        for (; j < cnt; ++j) {
            int s = __shfl(srcv, gbase + j);
            float4 hv = ldbf4(in + (size_t)s * 64 + l16 * 4);
            add4(acc, hv);
        }
    }
}

// ---------------- init ----------------

__global__ void zero_all_k(int* __restrict__ cursor, float* __restrict__ stats_all) {
    int i = blockIdx.x * blockDim.x + threadIdx.x;
    if (i < NN) cursor[i] = 0;
    if (i < 7 * 128) stats_all[i] = 0.f;
}

// ---------------- CSR build (counting sort by dst), 2 edges/thread ----------------

__global__ void hist_k(const int* __restrict__ dst, int* __restrict__ deg) {
    int e = (blockIdx.x * 256 + threadIdx.x) * 2;
    if (e + 2 <= EE) {
        int2 d = *(const int2*)&dst[e];
        atomicAdd(&deg[d.x], 1); atomicAdd(&deg[d.y], 1);
    } else {
        for (; e < EE; ++e) atomicAdd(&deg[dst[e]], 1);
    }
}

__global__ __launch_bounds__(1024) void scanA_k(const int* __restrict__ deg,
                                                int* __restrict__ rowstart,
                                                int* __restrict__ blocksum) {
    __shared__ int buf[1024];
    int tid = threadIdx.x;
    int base = blockIdx.x * 1024;
    int v = (base + tid < NN) ? deg[base + tid] : 0;
    buf[tid] = v;
    __syncthreads();
    for (int o = 1; o < 1024; o <<= 1) {
        int t = (tid >= o) ? buf[tid - o] : 0;
        __syncthreads();
        buf[tid] += t;
        __syncthreads();
    }
    if (base + tid < NN) rowstart[base + tid + 1] = buf[tid];
    if (tid == 1023) blocksum[blockIdx.x] = buf[1023];
}

__global__ void scanB_k(const int* __restrict__ blocksum, int* __restrict__ bofs, int nb) {
    int lane = threadIdx.x;  // 64 threads
    int v = (lane < nb) ? blocksum[lane] : 0;
    int orig = v;
    for (int o = 1; o < 64; o <<= 1) {
        int t = __shfl_up(v, o);
        if (lane >= o) v += t;
    }
    if (lane < nb) bofs[lane] = v - orig;
}

__global__ void scanC_k(int* __restrict__ rowstart, const int* __restrict__ bofs,
                        int* __restrict__ cursor) {
    int i = blockIdx.x * blockDim.x + threadIdx.x;
    if (i >= NN) return;
    int val = rowstart[i + 1] + bofs[i >> 10];
    rowstart[i + 1] = val;
    if (i + 1 < NN) cursor[i + 1] = val;
    if (i == 0) { rowstart[0] = 0; cursor[0] = 0; }
}

__global__ void fill_k(const int* __restrict__ src, const int* __restrict__ dst,
                       int* __restrict__ cursor, int* __restrict__ csr_src) {
    int e = (blockIdx.x * 256 + threadIdx.x) * 2;
    if (e + 2 <= EE) {
        int2 d = *(const int2*)&dst[e];
        int2 s = *(const int2*)&src[e];
        int p0 = atomicAdd(&cursor[d.x], 1);
        int p1 = atomicAdd(&cursor[d.y], 1);
        csr_src[p0] = s.x; csr_src[p1] = s.y;
    } else {
        for (; e < EE; ++e) { int p = atomicAdd(&cursor[dst[e]], 1); csr_src[p] = src[e]; }
    }
}

// ---------------- segment boundaries (batch is sorted) ----------------

__global__ void seg_bounds_k(const int* __restrict__ batch, int* __restrict__ segstart) {
    int g = blockIdx.x * blockDim.x + threadIdx.x;
    if (g > GG) return;
    int lo = 0, hi = NN;
    while (lo < hi) {
        int mid = (lo + hi) >> 1;
        if (batch[mid] < g) lo = mid + 1; else hi = mid;
    }
    segstart[g] = lo;
}

// ---------------- fused gather + W2 GEMM (layer 0 tail), 64-row tiles, 512 threads ----------------

__global__ __launch_bounds__(512) void agg_gemm_k(
    const u16* __restrict__ in,
    const int* __restrict__ rowstart, const int* __restrict__ csr_src,
    const float* __restrict__ bias1,
    const float* __restrict__ W2, const float* __restrict__ bias2,
    u16* __restrict__ out, float* __restrict__ gstats)
{
    constexpr int KP = 68;
    __shared__ float sW[64 * 64];
    __shared__ float sIn[64 * KP];
    __shared__ float sStat[128];
    const int tid = threadIdx.x;

    for (int i = tid; i < 64 * 16; i += 512) ((float4*)sW)[i] = ((const float4*)W2)[i];

    const int tile = blockIdx.x * 64;
    const int nrows = min(64, NN - tile);
    const int l16 = tid & 15, gbase = (tid & 63) & 48, grp = tid >> 4;  // 32 groups
    float4 b1v = ((const float4*)bias1)[l16];
    for (int r = grp; r < nrows; r += 32) {
        int node = tile + r;
        float4 acc = ldbf4(in + (size_t)node * 64 + l16 * 4);
        gather16(acc, in, csr_src, rowstart[node], rowstart[node + 1], l16, gbase);
        acc.x = fmaxf(acc.x + b1v.x, 0.f); acc.y = fmaxf(acc.y + b1v.y, 0.f);
        acc.z = fmaxf(acc.z + b1v.z, 0.f); acc.w = fmaxf(acc.w + b1v.w, 0.f);
        *(float4*)&sIn[r * KP + l16 * 4] = acc;
    }
    __syncthreads();

    const int rg = (tid >> 4) * 2, c0 = (tid & 15) << 2;
    float4 bb = *(const float4*)&bias2[c0];
    float4 acc[2] = {bb, bb};
#pragma unroll 2
    for (int k4 = 0; k4 < 16; ++k4) {
        float4 av0 = *(const float4*)&sIn[rg * KP + k4 * 4];
        float4 av1 = *(const float4*)&sIn[(rg + 1) * KP + k4 * 4];
        const float* wp = &sW[k4 * 4 * 64 + c0];
        float4 w0 = *(const float4*)(wp);
        float4 w1 = *(const float4*)(wp + 64);
        float4 w2 = *(const float4*)(wp + 128);
        float4 w3 = *(const float4*)(wp + 192);
        fma4(acc[0], w0, av0.x); fma4(acc[0], w1, av0.y);
        fma4(acc[0], w2, av0.z); fma4(acc[0], w3, av0.w);
        fma4(acc[1], w0, av1.x); fma4(acc[1], w1, av1.y);
        fma4(acc[1], w2, av1.z); fma4(acc[1], w3, av1.w);
    }
#pragma unroll
    for (int j = 0; j < 2; ++j) {
        acc[j].x = fmaxf(acc[j].x, 0.f); acc[j].y = fmaxf(acc[j].y, 0.f);
        acc[j].z = fmaxf(acc[j].z, 0.f); acc[j].w = fmaxf(acc[j].w, 0.f);
        if (rg + j < nrows) stbf4(out + (size_t)(tile + rg + j) * 64 + c0, acc[j]);
    }
    if (tid < 128) sStat[tid] = 0.f;
    __syncthreads();
    float sx = 0, sy = 0, sz = 0, sw = 0, qx = 0, qy = 0, qz = 0, qw = 0;
#pragma unroll
    for (int j = 0; j < 2; ++j) {
        if (rg + j < nrows) {
            sx += acc[j].x; sy += acc[j].y; sz += acc[j].z; sw += acc[j].w;
            qx += acc[j].x * acc[j].x; qy += acc[j].y * acc[j].y;
            qz += acc[j].z * acc[j].z; qw += acc[j].w * acc[j].w;
        }
    }
    atomicAdd(&sStat[c0 + 0], sx); atomicAdd(&sStat[c0 + 1], sy);
    atomicAdd(&sStat[c0 + 2], sz); atomicAdd(&sStat[c0 + 3], sw);
    atomicAdd(&sStat[64 + c0 + 0], qx); atomicAdd(&sStat[64 + c0 + 1], qy);
    atomicAdd(&sStat[64 + c0 + 2], qz); atomicAdd(&sStat[64 + c0 + 3], qw);
    __syncthreads();
    if (tid < 128) atomicAdd(&gstats[tid], sStat[tid]);
}

// ---------------- fully fused GIN layer (layers 1,2), 64-row tiles, 512 threads ----------------

__global__ __launch_bounds__(512) void fused_layer_k(
    const u16* __restrict__ in,
    const int* __restrict__ rowstart, const int* __restrict__ csr_src,
    const float* __restrict__ bnst, const float* __restrict__ gam, const float* __restrict__ bet,
    const float* __restrict__ W1, const float* __restrict__ b1,
    const float* __restrict__ W2, const float* __restrict__ b2,
    u16* __restrict__ out, float* __restrict__ gstats)
{
    constexpr int KP = 68;
    __shared__ float sW[64 * 64];      // W1 then reloaded with W2
    __shared__ float sAgg[64 * KP];
    __shared__ float sStat[128];
    __shared__ float aL[64], dL[64];
    const int tid = threadIdx.x;

    for (int i = tid; i < 64 * 16; i += 512) ((float4*)sW)[i] = ((const float4*)W1)[i];
    if (tid < 64) {
        float m = bnst[tid] * (1.f / NN);
        float v = bnst[64 + tid] * (1.f / NN) - m * m;
        float a = rsqrtf(v + 1e-5f) * gam[tid];
        aL[tid] = a;
        dL[tid] = bet[tid] - m * a;
    }
    __syncthreads();

    const int tile = blockIdx.x * 64;
    const int nrows = min(64, NN - tile);
    const int l16 = tid & 15, gbase = (tid & 63) & 48, grp = tid >> 4;  // 32 groups
    float4 av4 = *(const float4*)&aL[l16 * 4];
    float4 dv4 = *(const float4*)&dL[l16 * 4];
    for (int r = grp; r < nrows; r += 32) {
        int node = tile + r;
        int e0s = rowstart[node], e1s = rowstart[node + 1];
        float4 acc = ldbf4(in + (size_t)node * 64 + l16 * 4);
        gather16(acc, in, csr_src, e0s, e1s, l16, gbase);
        float dp1 = (float)(e1s - e0s + 1);
        acc.x = fmaf(av4.x, acc.x, dp1 * dv4.x);
        acc.y = fmaf(av4.y, acc.y, dp1 * dv4.y);
        acc.z = fmaf(av4.z, acc.z, dp1 * dv4.z);
        acc.w = fmaf(av4.w, acc.w, dp1 * dv4.w);
        *(float4*)&sAgg[r * KP + l16 * 4] = acc;
    }
    __syncthreads();

    const int rg = (tid >> 4) * 2, c0 = (tid & 15) << 2;
    // GEMM1: T1 = relu(sAgg @ W1 + b1) into registers
    float4 t[2];
    {
        float4 bb = *(const float4*)&b1[c0];
        t[0] = bb; t[1] = bb;
#pragma unroll 2
        for (int k4 = 0; k4 < 16; ++k4) {
            float4 av0 = *(const float4*)&sAgg[rg * KP + k4 * 4];
            float4 av1 = *(const float4*)&sAgg[(rg + 1) * KP + k4 * 4];
            const float* wp = &sW[k4 * 4 * 64 + c0];
            float4 w0 = *(const float4*)(wp);
            float4 w1 = *(const float4*)(wp + 64);
            float4 w2 = *(const float4*)(wp + 128);
            float4 w3 = *(const float4*)(wp + 192);
            fma4(t[0], w0, av0.x); fma4(t[0], w1, av0.y);
            fma4(t[0], w2, av0.z); fma4(t[0], w3, av0.w);
            fma4(t[1], w0, av1.x); fma4(t[1], w1, av1.y);
            fma4(t[1], w2, av1.z); fma4(t[1], w3, av1.w);
        }
#pragma unroll
        for (int j = 0; j < 2; ++j) {
            t[j].x = fmaxf(t[j].x, 0.f); t[j].y = fmaxf(t[j].y, 0.f);
            t[j].z = fmaxf(t[j].z, 0.f); t[j].w = fmaxf(t[j].w, 0.f);
        }
    }
    __syncthreads();   // all reads of sW(W1)+sAgg done

    // reload W2 into sW; write T1 back into sAgg
    for (int i = tid; i < 64 * 16; i += 512) ((float4*)sW)[i] = ((const float4*)W2)[i];
#pragma unroll
    for (int j = 0; j < 2; ++j) *(float4*)&sAgg[(rg + j) * KP + c0] = t[j];
    __syncthreads();

    // GEMM2: out = relu(T1 @ W2 + b2), stats
    float4 acc[2];
    {
        float4 bb = *(const float4*)&b2[c0];
        acc[0] = bb; acc[1] = bb;
#pragma unroll 2
        for (int k4 = 0; k4 < 16; ++k4) {
            float4 av0 = *(const float4*)&sAgg[rg * KP + k4 * 4];
            float4 av1 = *(const float4*)&sAgg[(rg + 1) * KP + k4 * 4];
            const float* wp = &sW[k4 * 4 * 64 + c0];
            float4 w0 = *(const float4*)(wp);
            float4 w1 = *(const float4*)(wp + 64);
            float4 w2 = *(const float4*)(wp + 128);
            float4 w3 = *(const float4*)(wp + 192);
            fma4(acc[0], w0, av0.x); fma4(acc[0], w1, av0.y);
            fma4(acc[0], w2, av0.z); fma4(acc[0], w3, av0.w);
            fma4(acc[1], w0, av1.x); fma4(acc[1], w1, av1.y);
            fma4(acc[1], w2, av1.z); fma4(acc[1], w3, av1.w);
        }
    }
#pragma unroll
    for (int j = 0; j < 2; ++j) {
        acc[j].x = fmaxf(acc[j].x, 0.f); acc[j].y = fmaxf(acc[j].y, 0.f);
        acc[j].z = fmaxf(acc[j].z, 0.f); acc[j].w = fmaxf(acc[j].w, 0.f);
        if (rg + j < nrows) stbf4(out + (size_t)(tile + rg + j) * 64 + c0, acc[j]);
    }
    if (tid < 128) sStat[tid] = 0.f;
    __syncthreads();
    float sx = 0, sy = 0, sz = 0, sw = 0, qx = 0, qy = 0, qz = 0, qw = 0;
#pragma unroll
    for (int j = 0; j < 2; ++j) {
        if (rg + j < nrows) {
            sx += acc[j].x; sy += acc[j].y; sz += acc[j].z; sw += acc[j].w;
            qx += acc[j].x * acc[j].x; qy += acc[j].y * acc[j].y;
            qz += acc[j].z * acc[j].z; qw += acc[j].w * acc[j].w;
        }
    }
    atomicAdd(&sStat[c0 + 0], sx); atomicAdd(&sStat[c0 + 1], sy);
    atomicAdd(&sStat[c0 + 2], sz); atomicAdd(&sStat[c0 + 3], sw);
    atomicAdd(&sStat[64 + c0 + 0], qx); atomicAdd(&sStat[64 + c0 + 1], qy);
    atomicAdd(&sStat[64 + c0 + 2], qz); atomicAdd(&sStat[64 + c0 + 3], qw);
    __syncthreads();
    if (tid < 128) atomicAdd(&gstats[tid], sStat[tid]);
}

// ---------------- skinny fp32 GEMM, templated bf16 in/out ----------------

template<int K, bool BIAS, bool RELU, bool STATS, bool ROWSCALE, bool BNIN, bool DUAL,
         bool INBF, bool OUTBF>
__global__ __launch_bounds__(256) void gemm_k(
    const void* __restrict__ in, const float* __restrict__ W, const float* __restrict__ Wb,
    const float* __restrict__ bias, const float* __restrict__ bias2,
    void* __restrict__ out, void* __restrict__ out2, int rows,
    float* __restrict__ gstats, float* __restrict__ gstats2,
    const float* __restrict__ attn, const float* __restrict__ noise,
    const float* __restrict__ bnstats, const float* __restrict__ gamma,
    const float* __restrict__ beta)
{
    constexpr int RPT = (K == 128) ? 2 : 4;
    constexpr int TR  = 16 * RPT;
    constexpr int KP  = K + 4;
    constexpr int SS  = DUAL ? 256 : 128;
    __shared__ float sW[K * 64];
    __shared__ float sWb[DUAL ? K * 64 : 4];
    __shared__ float sIn[TR * KP];
    __shared__ float sStat[STATS ? SS : 4];
    __shared__ float sA[BNIN ? 64 : 4];
    __shared__ float sD[BNIN ? 64 : 4];

    const int tid = threadIdx.x;
    for (int i = tid; i < K * 16; i += 256) ((float4*)sW)[i] = ((const float4*)W)[i];
    if (DUAL)
        for (int i = tid; i < K * 16; i += 256) ((float4*)sWb)[i] = ((const float4*)Wb)[i];
    if (BNIN && tid < 64) {
        float m   = bnstats[tid] * (1.f / NN);
        float v   = bnstats[64 + tid] * (1.f / NN) - m * m;
        float a   = rsqrtf(v + 1e-5f) * gamma[tid];
        sA[tid] = a;
        sD[tid] = beta[tid] - m * a;
    }

    int rg = (tid >> 4) * RPT;
    int c0 = (tid & 15) << 2;
    float4 bb  = make_float4(0.f, 0.f, 0.f, 0.f);
    float4 bb2 = make_float4(0.f, 0.f, 0.f, 0.f);
    if (BIAS) bb = *(const float4*)&bias[c0];
    if (BIAS && DUAL) bb2 = *(const float4*)&bias2[c0];

    for (int tile = blockIdx.x * TR; tile < rows; tile += gridDim.x * TR) {
        __syncthreads();
        int nrows = min(TR, rows - tile);
        const float4* igf = INBF ? nullptr : (const float4*)((const float*)in + (size_t)tile * K);
        const u16*    igb = INBF ? ((const u16*)in + (size_t)tile * K) : nullptr;
        const float4* ng  = ROWSCALE ? (const float4*)(noise + (size_t)tile * K) : nullptr;
        for (int i = tid; i < nrows * (K / 4); i += 256) {
            int rr = i / (K / 4), kk = (i - rr * (K / 4)) * 4;
            float4 t = INBF ? ldbf4(igb + i * 4) : igf[i];
            if (BNIN) {
                t.x = fmaf(sA[kk + 0], t.x, sD[kk + 0]);
                t.y = fmaf(sA[kk + 1], t.y, sD[kk + 1]);
                t.z = fmaf(sA[kk + 2], t.z, sD[kk + 2]);
                t.w = fmaf(sA[kk + 3], t.w, sD[kk + 3]);
            }
            if (ROWSCALE) {
                float4 nv = ng[i];
                float at = attn[tile + rr];
                t.x = fmaf(at, t.x, nv.x); t.y = fmaf(at, t.y, nv.y);
                t.z = fmaf(at, t.z, nv.z); t.w = fmaf(at, t.w, nv.w);
            }
            *(float4*)&sIn[rr * KP + kk] = t;
        }
        __syncthreads();

        float4 acc[RPT];
        float4 acc2[DUAL ? RPT : 1];
#pragma unroll
        for (int j = 0; j < RPT; ++j) acc[j] = bb;
        if (DUAL) {
#pragma unroll
            for (int j = 0; j < RPT; ++j) acc2[j] = bb2;
        }
#pragma unroll 2
        for (int k4 = 0; k4 < K / 4; ++k4) {
            float4 av[RPT];
#pragma unroll
            for (int j = 0; j < RPT; ++j)
                av[j] = *(const float4*)&sIn[(rg + j) * KP + k4 * 4];
            const float* wp = &sW[k4 * 4 * 64 + c0];
            float4 w0 = *(const float4*)(wp);
            float4 w1 = *(const float4*)(wp + 64);
            float4 w2 = *(const float4*)(wp + 128);
            float4 w3 = *(const float4*)(wp + 192);
#pragma unroll
            for (int j = 0; j < RPT; ++j) {
                fma4(acc[j], w0, av[j].x); fma4(acc[j], w1, av[j].y);
                fma4(acc[j], w2, av[j].z); fma4(acc[j], w3, av[j].w);
            }
            if (DUAL) {
                const float* wq = &sWb[k4 * 4 * 64 + c0];
                float4 u0 = *(const float4*)(wq);
                float4 u1 = *(const float4*)(wq + 64);
                float4 u2 = *(const float4*)(wq + 128);
                float4 u3 = *(const float4*)(wq + 192);
#pragma unroll
                for (int j = 0; j < RPT; ++j) {
                    fma4(acc2[j], u0, av[j].x); fma4(acc2[j], u1, av[j].y);
                    fma4(acc2[j], u2, av[j].z); fma4(acc2[j], u3, av[j].w);
                }
            }
        }
        if (RELU) {
#pragma unroll
            for (int j = 0; j < RPT; ++j) {
                acc[j].x = fmaxf(acc[j].x, 0.f); acc[j].y = fmaxf(acc[j].y, 0.f);
                acc[j].z = fmaxf(acc[j].z, 0.f); acc[j].w = fmaxf(acc[j].w, 0.f);
                if (DUAL) {
                    acc2[j].x = fmaxf(acc2[j].x, 0.f); acc2[j].y = fmaxf(acc2[j].y, 0.f);
                    acc2[j].z = fmaxf(acc2[j].z, 0.f); acc2[j].w = fmaxf(acc2[j].w, 0.f);
                }
            }
        }
#pragma unroll
        for (int j = 0; j < RPT; ++j) {
            int r = rg + j;
            if (r < nrows) {
                if (OUTBF) stbf4((u16*)out + (size_t)(tile + r) * 64 + c0, acc[j]);
                else *(float4*)((float*)out + (size_t)(tile + r) * 64 + c0) = acc[j];
                if (DUAL) {
                    if (OUTBF) stbf4((u16*)out2 + (size_t)(tile + r) * 64 + c0, acc2[j]);
                    else *(float4*)((float*)out2 + (size_t)(tile + r) * 64 + c0) = acc2[j];
                }
            }
        }
        if (STATS) {
            if (tid < SS) sStat[tid] = 0.f;
            __syncthreads();
            float sx = 0, sy = 0, sz = 0, sw = 0, qx = 0, qy = 0, qz = 0, qw = 0;
            float sx2 = 0, sy2 = 0, sz2 = 0, sw2 = 0, qx2 = 0, qy2 = 0, qz2 = 0, qw2 = 0;
#pragma unroll
            for (int j = 0; j < RPT; ++j) {
                if (rg + j < nrows) {
                    sx += acc[j].x; sy += acc[j].y; sz += acc[j].z; sw += acc[j].w;
                    qx += acc[j].x * acc[j].x; qy += acc[j].y * acc[j].y;
                    qz += acc[j].z * acc[j].z; qw += acc[j].w * acc[j].w;
                    if (DUAL) {
                        sx2 += acc2[j].x; sy2 += acc2[j].y; sz2 += acc2[j].z; sw2 += acc2[j].w;
                        qx2 += acc2[j].x * acc2[j].x; qy2 += acc2[j].y * acc2[j].y;
                        qz2 += acc2[j].z * acc2[j].z; qw2 += acc2[j].w * acc2[j].w;
                    }
                }
            }
            atomicAdd(&sStat[c0 + 0], sx); atomicAdd(&sStat[c0 + 1], sy);
            atomicAdd(&sStat[c0 + 2], sz); atomicAdd(&sStat[c0 + 3], sw);
            atomicAdd(&sStat[64 + c0 + 0], qx); atomicAdd(&sStat[64 + c0 + 1], qy);
            atomicAdd(&sStat[64 + c0 + 2], qz); atomicAdd(&sStat[64 + c0 + 3], qw);
            if (DUAL) {
                atomicAdd(&sStat[128 + c0 + 0], sx2); atomicAdd(&sStat[128 + c0 + 1], sy2);
                atomicAdd(&sStat[128 + c0 + 2], sz2); atomicAdd(&sStat[128 + c0 + 3], sw2);
                atomicAdd(&sStat[192 + c0 + 0], qx2); atomicAdd(&sStat[192 + c0 + 1], qy2);
                atomicAdd(&sStat[192 + c0 + 2], qz2); atomicAdd(&sStat[192 + c0 + 3], qw2);
            }
            __syncthreads();
            if (tid < 128) atomicAdd(&gstats[tid], sStat[tid]);
            if (DUAL && tid >= 128) atomicAdd(&gstats2[tid - 128], sStat[tid]);
        }
    }
}

// ---------------- paired batchnorm apply: bf16 inputs (node heads) ----------------

__global__ void bn_apply2b_k(const u16* __restrict__ in1, const u16* __restrict__ in2,
                             float* __restrict__ out1, float* __restrict__ out2, int rows,
                             const float* __restrict__ st1, const float* __restrict__ st2,
                             const float* __restrict__ g1, const float* __restrict__ b1,
                             const float* __restrict__ g2, const float* __restrict__ b2) {
    int n = rows * 64;
    float invr = 1.f / (float)rows;
    for (int i = blockIdx.x * blockDim.x + threadIdx.x; i < n; i += gridDim.x * blockDim.x) {
        int c = i & 63;
        float m1 = st1[c] * invr;
        float v1 = st1[64 + c] * invr - m1 * m1;
        out1[i] = (bf2f(in1[i]) - m1) * rsqrtf(v1 + 1e-5f) * g1[c] + b1[c];
        float m2 = st2[c] * invr;
        float v2 = st2[64 + c] * invr - m2 * m2;
        out2[i] = (bf2f(in2[i]) - m2) * rsqrtf(v2 + 1e-5f) * g2[c] + b2[c];
    }
}

// ---------------- paired batchnorm apply: fp32 inputs (graph heads) ----------------

__global__ void bn_apply2_k(const float* __restrict__ in1, const float* __restrict__ in2,
                            float* __restrict__ out1, float* __restrict__ out2, int rows,
                            const float* __restrict__ st1, const float* __restrict__ st2,
                            const float* __restrict__ g1, const float* __restrict__ b1,
                            const float* __restrict__ g2, const float* __restrict__ b2) {
    int n = rows * 64;
    float invr = 1.f / (float)rows;
    for (int i = blockIdx.x * blockDim.x + threadIdx.x; i < n; i += gridDim.x * blockDim.x) {
        int c = i & 63;
        float m1 = st1[c] * invr;
        float v1 = st1[64 + c] * invr - m1 * m1;
        out1[i] = (in1[i] - m1) * rsqrtf(v1 + 1e-5f) * g1[c] + b1[c];
        float m2 = st2[c] * invr;
        float v2 = st2[64 + c] * invr - m2 * m2;
        out2[i] = (in2[i] - m2) * rsqrtf(v2 + 1e-5f) * g2[c] + b2[c];
    }
}

// ---------------- attention on z (bf16) directly; k/v never materialized ----------------

__global__ __launch_bounds__(256) void attn3_k(
    const u16* __restrict__ z, const int* __restrict__ segst,
    const float* __restrict__ bnst, const float* __restrict__ gam, const float* __restrict__ bet,
    const float* __restrict__ Wq, const float* __restrict__ Wk, const float* __restrict__ Wv,
    const float* __restrict__ Wih, const float* __restrict__ Whh,
    const float* __restrict__ bih, const float* __restrict__ bhh,
    float* __restrict__ attn, float* __restrict__ slots_out)
{
    int g = blockIdx.x, tid = threadIdx.x, w = tid >> 6, lane = tid & 63;
    __shared__ float ssl[64], sq[64], swr[64], sm[64], supd[64], sred[256], ssum[4];
    __shared__ float aL[64], dL[64];
    __shared__ float sgi[192], sgh[192];
    __shared__ float sc, sinv;

    int s0 = segst[g], s1 = segst[g + 1];
    if (tid < 64) {
        float m = bnst[tid] * (1.f / NN);
        float v = bnst[64 + tid] * (1.f / NN) - m * m;
        float a = rsqrtf(v + 1e-5f) * gam[tid];
        aL[tid] = a;
        dL[tid] = bet[tid] - m * a;
    }
    __syncthreads();

    {
        float macc = 0.f;
        for (int n = s0 + w; n < s1; n += 4) macc += bf2f(z[(size_t)n * 64 + lane]);
        sred[tid] = macc;
        __syncthreads();
        if (tid < 64) {
            float mean = (sred[tid] + sred[64 + tid] + sred[128 + tid] + sred[192 + tid])
                       / (float)max(s1 - s0, 1);
            ssl[tid] = fmaf(aL[tid], mean, dL[tid]);
        }
        __syncthreads();
    }

    for (int it = 0; it < 2; ++it) {
        {
            float p = 0.f;
#pragma unroll
            for (int kk = 0; kk < 16; ++kk) p += ssl[w * 16 + kk] * Wq[(w * 16 + kk) * 64 + lane];
            sred[tid] = p;
        }
        __syncthreads();
        if (tid < 64) sq[tid] = sred[tid] + sred[64 + tid] + sred[128 + tid] + sred[192 + tid];
        __syncthreads();
        {
            float p = 0.f;
#pragma unroll
            for (int kk = 0; kk < 16; ++kk) p += Wk[lane * 64 + w * 16 + kk] * sq[w * 16 + kk];
            sred[tid] = p;
        }
        __syncthreads();
        if (tid < 64) swr[tid] = sred[tid] + sred[64 + tid] + sred[128 + tid] + sred[192 + tid];
        __syncthreads();
        if (tid < 64) {
            float pr = dL[tid] * swr[tid];
            pr += __shfl_xor(pr, 1);  pr += __shfl_xor(pr, 2);  pr += __shfl_xor(pr, 4);
            pr += __shfl_xor(pr, 8);  pr += __shfl_xor(pr, 16); pr += __shfl_xor(pr, 32);
            if (tid == 0) sc = pr * 0.125f;
            swr[tid] = aL[tid] * swr[tid] * 0.125f;
        }
        __syncthreads();
        float wl = swr[lane], cc = sc;

        float s = 0.f, u = 0.f;
        for (int n = s0 + w; n < s1; n += 4) {
            float zl = bf2f(z[(size_t)n * 64 + lane]);
            float l = zl * wl;
            l += __shfl_xor(l, 1);  l += __shfl_xor(l, 2);  l += __shfl_xor(l, 4);
            l += __shfl_xor(l, 8);  l += __shfl_xor(l, 16); l += __shfl_xor(l, 32);
            float e = expf(l + cc);
            if (lane == 0) attn[n] = e;
            s += e;
            u = fmaf(e, zl, u);
        }
        sred[tid] = u;
        if (lane == 0) ssum[w] = s;
        __syncthreads();
        if (tid < 64) {
            float stot = ssum[0] + ssum[1] + ssum[2] + ssum[3] + 1e-9f;
            if (tid == 0) sinv = 1.f / stot;
            float uu = sred[tid] + sred[64 + tid] + sred[128 + tid] + sred[192 + tid];
            sm[tid] = fmaf(aL[tid], uu / stot, dL[tid]);
        }
        __syncthreads();
        {
            float p = 0.f;
#pragma unroll
            for (int kk = 0; kk < 16; ++kk) p += sm[w * 16 + kk] * Wv[(w * 16 + kk) * 64 + lane];
            sred[tid] = p;
        }
        __syncthreads();
        if (tid < 64) supd[tid] = sred[tid] + sred[64 + tid] + sred[128 + tid] + sred[192 + tid];
        __syncthreads();

        if (it == 1) {
            float inv = sinv;
            for (int n = s0 + tid; n < s1; n += 256) attn[n] *= inv;
        }

        if (tid < 192) {
            float a = bih[tid], b = bhh[tid];
            const float* wi = &Wih[tid * 64];
            const float* wh = &Whh[tid * 64];
#pragma unroll 8
            for (int j = 0; j < 64; ++j) { a += supd[j] * wi[j]; b += ssl[j] * wh[j]; }
            sgi[tid] = a; sgh[tid] = b;
        }
        __syncthreads();
        if (tid < 64) {
            float r  = 1.f / (1.f + expf(-(sgi[tid] + sgh[tid])));
            float zz = 1.f / (1.f + expf(-(sgi[64 + tid] + sgh[64 + tid])));
            float nn = tanhf(sgi[128 + tid] + r * sgh[128 + tid]);
            float ns = (1.f - zz) * nn + zz * ssl[tid];
            ssl[tid] = ns;
            if (it == 1) slots_out[g * 64 + tid] = ns;
        }
        __syncthreads();
    }
}

// ---------------- host side ----------------

extern "C" void kernel_launch(void* const* d_in, const int* in_sizes, int n_in,
                              void* d_out, int out_size, void* d_ws, size_t ws_size,
                              hipStream_t stream) {
    (void)in_sizes; (void)n_in; (void)out_size; (void)ws_size;

    const float* x      = (const float*)d_in[0];
    const int*   ei     = (const int*)d_in[1];
    const int*   srcI   = ei;
    const int*   dstI   = ei + EE;
    const int*   batch  = (const int*)d_in[2];
    const float* noise  = (const float*)d_in[3];
    const float* W1_0   = (const float*)d_in[4];
    const float* b1_0   = (const float*)d_in[5];
    const float* W2_0   = (const float*)d_in[6];
    const float* b2_0   = (const float*)d_in[7];
    const float* W1_r   = (const float*)d_in[8];
    const float* b1_r   = (const float*)d_in[9];
    const float* W2_r   = (const float*)d_in[10];
    const float* b2_r   = (const float*)d_in[11];
    const float* bn_g   = (const float*)d_in[12];
    const float* bn_b   = (const float*)d_in[13];
    const float* Wq     = (const float*)d_in[14];
    const float* Wk     = (const float*)d_in[15];
    const float* Wv     = (const float*)d_in[16];
    const float* Wih    = (const float*)d_in[17];
    const float* Whh    = (const float*)d_in[18];
    const float* bih    = (const float*)d_in[19];
    const float* bhh    = (const float*)d_in[20];
    const float* nmW    = (const float*)d_in[21];
    const float* nmb    = (const float*)d_in[22];
    const float* nlW    = (const float*)d_in[23];
    const float* nlb    = (const float*)d_in[24];
    const float* gmW    = (const float*)d_in[25];
    const float* gmb    = (const float*)d_in[26];
    const float* glW    = (const float*)d_in[27];
    const float* glb    = (const float*)d_in[28];
    const float* pj_g   = (const float*)d_in[29];
    const float* pj_b   = (const float*)d_in[30];

    char* w = (char*)d_ws;
    u16*   B0b   = (u16*)w;            w += (size_t)NN * 64 * 2;
    u16*   B1b   = (u16*)w;            w += (size_t)NN * 64 * 2;
    u16*   B2b   = (u16*)w;            w += (size_t)NN * 64 * 2;
    float* slots = (float*)w;          w += GG * 64 * 4;
    float* gpre1 = (float*)w;          w += GG * 64 * 4;
    float* gpre2 = (float*)w;          w += GG * 64 * 4;
    float* attn  = (float*)w;          w += NN * 4;
    float* stats = (float*)w;          w += 7 * 128 * 4;
    int*   segst = (int*)w;            w += (GG + 1) * 4;
    int*   rowst = (int*)w;            w += (NN + 1) * 4;
    int*   cursor= (int*)w;            w += NN * 4;
    int*   bsum  = (int*)w;            w += 64 * 4;
    int*   bofs  = (int*)w;            w += 64 * 4;
    int*   csr   = (int*)w;            w += (size_t)EE * 4;

    float* s0 = stats, *s1 = stats + 128, *s2 = stats + 256, *s3 = stats + 384,
         * s4 = stats + 512, *s5 = stats + 640, *s6 = stats + 768;

    float* outp = (float*)d_out;
    float* out_nmu = outp;
    float* out_nlv = outp + NN * DD;
    float* out_gmu = outp + 2 * NN * DD;
    float* out_glv = outp + 2 * NN * DD + GG * DD;

    constexpr int NB = (NN + 1023) / 1024;       // 49 scan chunks
    constexpr int GE2 = (EE / 2 + 255) / 256;    // 1563 (2 edges/thread)
    constexpr int NT64 = (NN + 63) / 64;         // 782 64-row tiles
    const float* np = nullptr;
    float* zp = nullptr;

#define GK(...) <<<__VA_ARGS__, 0, stream>>>
    // ---------- init + CSR build + segments ----------
    zero_all_k GK((NN + 255) / 256, 256)(cursor, stats);
    hist_k GK(GE2, 256)(dstI, cursor);
    scanA_k GK(NB, 1024)(cursor, rowst, bsum);
    scanB_k GK(1, 64)(bsum, bofs, NB);
    scanC_k GK((NN + 255) / 256, 256)(rowst, bofs, cursor);
    fill_k GK(GE2, 256)(srcI, dstI, cursor, csr);
    seg_bounds_k GK(3, 256)(batch, segst);

    // ---------- GIN layer 0: x@W1 (K=128, fp32 in -> bf16 out), fused gather+W2 ----------
    gemm_k<128,false,false,false,false,false,false,false,true> GK(1563, 256)
        (x, W1_0, np, np, np, B0b, zp, NN, zp, zp, np, np, np, np, np);
    agg_gemm_k GK(NT64, 512)(B0b, rowst, csr, b1_0, W2_0, b2_0, B1b, s0);

    // ---------- GIN layers 1,2 (fully fused; bf16 in/out; 64-row tiles, 512 threads) ----------
    fused_layer_k GK(NT64, 512)(B1b, rowst, csr, s0, bn_g + 0, bn_b + 0,
                                W1_r, b1_r, W2_r, b2_r, B2b, s1);
    fused_layer_k GK(NT64, 512)(B2b, rowst, csr, s1, bn_g + 64, bn_b + 64,
                                W1_r + DD * DD, b1_r + DD, W2_r + DD * DD, b2_r + DD, B0b, s2);
    // B0b = z2 (pre-BN, relu'd, bf16); BN2 affine (s2, bn[2]) fused into all consumers.

    // ---------- summary maker: attention directly on z2 ----------
    attn3_k GK(GG, 256)(B0b, segst, s2, bn_g + 128, bn_b + 128,
                        Wq, Wk, Wv, Wih, Whh, bih, bhh, attn, slots);

    // ---------- node heads (noisy fused; bf16 outs into dead B1b/B2b) ----------
    gemm_k<64,true,true,true,true,true,true,true,true> GK(782, 256)
        (B0b, nmW, nlW, nmb, nlb, B1b, B2b, NN, s3, s4, attn, noise, s2, bn_g + 128, bn_b + 128);
    bn_apply2b_k GK(2048, 256)(B1b, B2b, out_nmu, out_nlv, NN, s3, s4,
                               pj_g + 0, pj_b + 0, pj_g + 64, pj_b + 64);

    // ---------- graph heads ----------
    gemm_k<64,true,true,true,false,false,true,false,false> GK(8, 256)
        (slots, gmW, glW, gmb, glb, gpre1, gpre2, GG, s5, s6, np, np, np, np, np);
    bn_apply2_k GK(128, 256)(gpre1, gpre2, out_gmu, out_glv, GG, s5, s6,
                             pj_g + 128, pj_b + 128, pj_g + 192, pj_b + 192);
#undef GK
}

// Round 17
// 381.270 us; speedup vs baseline: 1.1444x; 1.1444x over previous
//
#include <hip/hip_runtime.h>

#define NN 50000
#define EE 800000
#define FF 128
#define DD 64
#define GG 512

typedef unsigned short u16;

// ---------------- bf16 storage helpers (compute stays fp32) ----------------

__device__ __forceinline__ float bf2f(u16 h) {
    unsigned u = ((unsigned)h) << 16;
    return __builtin_bit_cast(float, u);
}
__device__ __forceinline__ u16 f2bf(float f) {
    unsigned u = __builtin_bit_cast(unsigned, f);
    u += 0x7fffu + ((u >> 16) & 1u);   // RNE
    return (u16)(u >> 16);
}
__device__ __forceinline__ float4 ldbf4(const u16* p) {
    uint2 v = *(const uint2*)p;
    float4 r;
    r.x = bf2f((u16)(v.x & 0xffffu)); r.y = bf2f((u16)(v.x >> 16));
    r.z = bf2f((u16)(v.y & 0xffffu)); r.w = bf2f((u16)(v.y >> 16));
    return r;
}
__device__ __forceinline__ void stbf4(u16* p, float4 v) {
    uint2 o;
    o.x = (unsigned)f2bf(v.x) | ((unsigned)f2bf(v.y) << 16);
    o.y = (unsigned)f2bf(v.z) | ((unsigned)f2bf(v.w) << 16);
    *(uint2*)p = o;
}
__device__ __forceinline__ void fma4(float4& a, const float4& w, float s) {
    a.x = fmaf(s, w.x, a.x); a.y = fmaf(s, w.y, a.y);
    a.z = fmaf(s, w.z, a.z); a.w = fmaf(s, w.w, a.w);
}
__device__ __forceinline__ void add4(float4& a, float4 b) {
    a.x += b.x; a.y += b.y; a.z += b.z; a.w += b.w;
}

// 8-wide unrolled neighbor gather: 8 independent loads in flight per group
__device__ __forceinline__ void gather16(float4& acc, const u16* __restrict__ in,
                                         const u16* __restrict__ csr, int e0s, int e1s,
                                         int l16, int gbase) {
    for (int e0 = e0s; e0 < e1s; e0 += 16) {
        int cnt = min(16, e1s - e0);
        int srcv = (l16 < cnt) ? (int)csr[e0 + l16] : 0;
        int j = 0;
        for (; j + 8 <= cnt; j += 8) {
            int i0 = __shfl(srcv, gbase + j);
            int i1 = __shfl(srcv, gbase + j + 1);
            int i2 = __shfl(srcv, gbase + j + 2);
            int i3 = __shfl(srcv, gbase + j + 3);
            int i4 = __shfl(srcv, gbase + j + 4);
            int i5 = __shfl(srcv, gbase + j + 5);
            int i6 = __shfl(srcv, gbase + j + 6);
            int i7 = __shfl(srcv, gbase + j + 7);
            float4 h0 = ldbf4(in + (size_t)i0 * 64 + l16 * 4);
            float4 h1 = ldbf4(in + (size_t)i1 * 64 + l16 * 4);
            float4 h2 = ldbf4(in + (size_t)i2 * 64 + l16 * 4);
            float4 h3 = ldbf4(in + (size_t)i3 * 64 + l16 * 4);
            float4 h4 = ldbf4(in + (size_t)i4 * 64 + l16 * 4);
            float4 h5 = ldbf4(in + (size_t)i5 * 64 + l16 * 4);
            float4 h6 = ldbf4(in + (size_t)i6 * 64 + l16 * 4);
            float4 h7 = ldbf4(in + (size_t)i7 * 64 + l16 * 4);
            add4(h0, h1); add4(h2, h3); add4(h4, h5); add4(h6, h7);
            add4(h0, h2); add4(h4, h6);
            add4(h0, h4);
            add4(acc, h0);
        }
        for (; j + 4 <= cnt; j += 4) {
            int i0 = __shfl(srcv, gbase + j);
            int i1 = __shfl(srcv, gbase + j + 1);
            int i2 = __shfl(srcv, gbase + j + 2);
            int i3 = __shfl(srcv, gbase + j + 3);
            float4 h0 = ldbf4(in + (size_t)i0 * 64 + l16 * 4);
            float4 h1 = ldbf4(in + (size_t)i1 * 64 + l16 * 4);
            float4 h2 = ldbf4(in + (size_t)i2 * 64 + l16 * 4);
            float4 h3 = ldbf4(in + (size_t)i3 * 64 + l16 * 4);
            add4(h0, h1); add4(h2, h3); add4(h0, h2);
            add4(acc, h0);
        }
        for (; j < cnt; ++j) {
            int s = __shfl(srcv, gbase + j);
            float4 hv = ldbf4(in + (size_t)s * 64 + l16 * 4);
            add4(acc, hv);
        }
    }
}

// ---------------- init ----------------

__global__ void zero_all_k(int* __restrict__ cursor, float* __restrict__ stats_all) {
    int i = blockIdx.x * blockDim.x + threadIdx.x;
    if (i < NN) cursor[i] = 0;
    if (i < 7 * 128) stats_all[i] = 0.f;
}

// ---------------- CSR build (counting sort by dst), 2 edges/thread ----------------

__global__ void hist_k(const int* __restrict__ dst, int* __restrict__ deg) {
    int e = (blockIdx.x * 256 + threadIdx.x) * 2;
    if (e + 2 <= EE) {
        int2 d = *(const int2*)&dst[e];
        atomicAdd(&deg[d.x], 1); atomicAdd(&deg[d.y], 1);
    } else {
        for (; e < EE; ++e) atomicAdd(&deg[dst[e]], 1);
    }
}

__global__ __launch_bounds__(1024) void scanA_k(const int* __restrict__ deg,
                                                int* __restrict__ rowstart,
                                                int* __restrict__ blocksum) {
    __shared__ int buf[1024];
    int tid = threadIdx.x;
    int base = blockIdx.x * 1024;
    int v = (base + tid < NN) ? deg[base + tid] : 0;
    buf[tid] = v;
    __syncthreads();
    for (int o = 1; o < 1024; o <<= 1) {
        int t = (tid >= o) ? buf[tid - o] : 0;
        __syncthreads();
        buf[tid] += t;
        __syncthreads();
    }
    if (base + tid < NN) rowstart[base + tid + 1] = buf[tid];
    if (tid == 1023) blocksum[blockIdx.x] = buf[1023];
}

__global__ void scanB_k(const int* __restrict__ blocksum, int* __restrict__ bofs, int nb) {
    int lane = threadIdx.x;  // 64 threads
    int v = (lane < nb) ? blocksum[lane] : 0;
    int orig = v;
    for (int o = 1; o < 64; o <<= 1) {
        int t = __shfl_up(v, o);
        if (lane >= o) v += t;
    }
    if (lane < nb) bofs[lane] = v - orig;
}

__global__ void scanC_k(int* __restrict__ rowstart, const int* __restrict__ bofs,
                        int* __restrict__ cursor) {
    int i = blockIdx.x * blockDim.x + threadIdx.x;
    if (i >= NN) return;
    int val = rowstart[i + 1] + bofs[i >> 10];
    rowstart[i + 1] = val;
    if (i + 1 < NN) cursor[i + 1] = val;
    if (i == 0) { rowstart[0] = 0; cursor[0] = 0; }
}

__global__ void fill_k(const int* __restrict__ src, const int* __restrict__ dst,
                       int* __restrict__ cursor, u16* __restrict__ csr16) {
    int e = (blockIdx.x * 256 + threadIdx.x) * 2;
    if (e + 2 <= EE) {
        int2 d = *(const int2*)&dst[e];
        int2 s = *(const int2*)&src[e];
        int p0 = atomicAdd(&cursor[d.x], 1);
        int p1 = atomicAdd(&cursor[d.y], 1);
        csr16[p0] = (u16)s.x; csr16[p1] = (u16)s.y;
    } else {
        for (; e < EE; ++e) { int p = atomicAdd(&cursor[dst[e]], 1); csr16[p] = (u16)src[e]; }
    }
}

// ---------------- segment boundaries (batch is sorted) ----------------

__global__ void seg_bounds_k(const int* __restrict__ batch, int* __restrict__ segstart) {
    int g = blockIdx.x * blockDim.x + threadIdx.x;
    if (g > GG) return;
    int lo = 0, hi = NN;
    while (lo < hi) {
        int mid = (lo + hi) >> 1;
        if (batch[mid] < g) lo = mid + 1; else hi = mid;
    }
    segstart[g] = lo;
}

// ---------------- fused gather + W2 GEMM (layer 0 tail), 64-row tiles ----------------

__global__ __launch_bounds__(256) void agg_gemm_k(
    const u16* __restrict__ in,
    const int* __restrict__ rowstart, const u16* __restrict__ csr,
    const float* __restrict__ bias1,
    const float* __restrict__ W2, const float* __restrict__ bias2,
    u16* __restrict__ out, float* __restrict__ gstats)
{
    constexpr int KP = 68;
    __shared__ float sW[64 * 64];
    __shared__ float sIn[64 * KP];
    __shared__ float sStat[128];
    const int tid = threadIdx.x;

    for (int i = tid; i < 64 * 16; i += 256) ((float4*)sW)[i] = ((const float4*)W2)[i];

    const int tile = blockIdx.x * 64;
    const int nrows = min(64, NN - tile);
    const int l16 = tid & 15, gbase = tid & 48, grp = tid >> 4;
    float4 b1v = ((const float4*)bias1)[l16];
    for (int r = grp; r < nrows; r += 16) {
        int node = tile + r;
        float4 acc = ldbf4(in + (size_t)node * 64 + l16 * 4);
        gather16(acc, in, csr, rowstart[node], rowstart[node + 1], l16, gbase);
        acc.x = fmaxf(acc.x + b1v.x, 0.f); acc.y = fmaxf(acc.y + b1v.y, 0.f);
        acc.z = fmaxf(acc.z + b1v.z, 0.f); acc.w = fmaxf(acc.w + b1v.w, 0.f);
        *(float4*)&sIn[r * KP + l16 * 4] = acc;
    }
    __syncthreads();

    const int rg = (tid >> 4) * 4, c0 = (tid & 15) << 2;
    float4 bb = *(const float4*)&bias2[c0];
    float4 acc[4];
#pragma unroll
    for (int j = 0; j < 4; ++j) acc[j] = bb;
#pragma unroll 2
    for (int k4 = 0; k4 < 16; ++k4) {
        float4 av[4];
#pragma unroll
        for (int j = 0; j < 4; ++j) av[j] = *(const float4*)&sIn[(rg + j) * KP + k4 * 4];
        const float* wp = &sW[k4 * 4 * 64 + c0];
        float4 w0 = *(const float4*)(wp);
        float4 w1 = *(const float4*)(wp + 64);
        float4 w2 = *(const float4*)(wp + 128);
        float4 w3 = *(const float4*)(wp + 192);
#pragma unroll
        for (int j = 0; j < 4; ++j) {
            fma4(acc[j], w0, av[j].x); fma4(acc[j], w1, av[j].y);
            fma4(acc[j], w2, av[j].z); fma4(acc[j], w3, av[j].w);
        }
    }
#pragma unroll
    for (int j = 0; j < 4; ++j) {
        acc[j].x = fmaxf(acc[j].x, 0.f); acc[j].y = fmaxf(acc[j].y, 0.f);
        acc[j].z = fmaxf(acc[j].z, 0.f); acc[j].w = fmaxf(acc[j].w, 0.f);
        if (rg + j < nrows) stbf4(out + (size_t)(tile + rg + j) * 64 + c0, acc[j]);
    }
    if (tid < 128) sStat[tid] = 0.f;
    __syncthreads();
    float sx = 0, sy = 0, sz = 0, sw = 0, qx = 0, qy = 0, qz = 0, qw = 0;
#pragma unroll
    for (int j = 0; j < 4; ++j) {
        if (rg + j < nrows) {
            sx += acc[j].x; sy += acc[j].y; sz += acc[j].z; sw += acc[j].w;
            qx += acc[j].x * acc[j].x; qy += acc[j].y * acc[j].y;
            qz += acc[j].z * acc[j].z; qw += acc[j].w * acc[j].w;
        }
    }
    atomicAdd(&sStat[c0 + 0], sx); atomicAdd(&sStat[c0 + 1], sy);
    atomicAdd(&sStat[c0 + 2], sz); atomicAdd(&sStat[c0 + 3], sw);
    atomicAdd(&sStat[64 + c0 + 0], qx); atomicAdd(&sStat[64 + c0 + 1], qy);
    atomicAdd(&sStat[64 + c0 + 2], qz); atomicAdd(&sStat[64 + c0 + 3], qw);
    __syncthreads();
    if (tid < 128) atomicAdd(&gstats[tid], sStat[tid]);
}

// ---------------- fully fused GIN layer (layers 1,2), 64-row tiles ----------------

__global__ __launch_bounds__(256) void fused_layer_k(
    const u16* __restrict__ in,
    const int* __restrict__ rowstart, const u16* __restrict__ csr,
    const float* __restrict__ bnst, const float* __restrict__ gam, const float* __restrict__ bet,
    const float* __restrict__ W1, const float* __restrict__ b1,
    const float* __restrict__ W2, const float* __restrict__ b2,
    u16* __restrict__ out, float* __restrict__ gstats)
{
    constexpr int KP = 68;
    __shared__ float sW[64 * 64];      // W1 then reloaded with W2
    __shared__ float sAgg[64 * KP];
    __shared__ float sStat[128];
    __shared__ float aL[64], dL[64];
    const int tid = threadIdx.x;

    for (int i = tid; i < 64 * 16; i += 256) ((float4*)sW)[i] = ((const float4*)W1)[i];
    if (tid < 64) {
        float m = bnst[tid] * (1.f / NN);
        float v = bnst[64 + tid] * (1.f / NN) - m * m;
        float a = rsqrtf(v + 1e-5f) * gam[tid];
        aL[tid] = a;
        dL[tid] = bet[tid] - m * a;
    }
    __syncthreads();

    const int tile = blockIdx.x * 64;
    const int nrows = min(64, NN - tile);
    const int l16 = tid & 15, gbase = tid & 48, grp = tid >> 4;
    float4 av4 = *(const float4*)&aL[l16 * 4];
    float4 dv4 = *(const float4*)&dL[l16 * 4];
    for (int r = grp; r < nrows; r += 16) {
        int node = tile + r;
        int e0s = rowstart[node], e1s = rowstart[node + 1];
        float4 acc = ldbf4(in + (size_t)node * 64 + l16 * 4);
        gather16(acc, in, csr, e0s, e1s, l16, gbase);
        float dp1 = (float)(e1s - e0s + 1);
        acc.x = fmaf(av4.x, acc.x, dp1 * dv4.x);
        acc.y = fmaf(av4.y, acc.y, dp1 * dv4.y);
        acc.z = fmaf(av4.z, acc.z, dp1 * dv4.z);
        acc.w = fmaf(av4.w, acc.w, dp1 * dv4.w);
        *(float4*)&sAgg[r * KP + l16 * 4] = acc;
    }
    __syncthreads();

    const int rg = (tid >> 4) * 4, c0 = (tid & 15) << 2;
    float4 t[4];
    {
        float4 bb = *(const float4*)&b1[c0];
#pragma unroll
        for (int j = 0; j < 4; ++j) t[j] = bb;
#pragma unroll 2
        for (int k4 = 0; k4 < 16; ++k4) {
            float4 a0[4];
#pragma unroll
            for (int j = 0; j < 4; ++j) a0[j] = *(const float4*)&sAgg[(rg + j) * KP + k4 * 4];
            const float* wp = &sW[k4 * 4 * 64 + c0];
            float4 w0 = *(const float4*)(wp);
            float4 w1 = *(const float4*)(wp + 64);
            float4 w2 = *(const float4*)(wp + 128);
            float4 w3 = *(const float4*)(wp + 192);
#pragma unroll
            for (int j = 0; j < 4; ++j) {
                fma4(t[j], w0, a0[j].x); fma4(t[j], w1, a0[j].y);
                fma4(t[j], w2, a0[j].z); fma4(t[j], w3, a0[j].w);
            }
        }
#pragma unroll
        for (int j = 0; j < 4; ++j) {
            t[j].x = fmaxf(t[j].x, 0.f); t[j].y = fmaxf(t[j].y, 0.f);
            t[j].z = fmaxf(t[j].z, 0.f); t[j].w = fmaxf(t[j].w, 0.f);
        }
    }
    __syncthreads();

    for (int i = tid; i < 64 * 16; i += 256) ((float4*)sW)[i] = ((const float4*)W2)[i];
#pragma unroll
    for (int j = 0; j < 4; ++j) *(float4*)&sAgg[(rg + j) * KP + c0] = t[j];
    __syncthreads();

    float4 acc[4];
    {
        float4 bb = *(const float4*)&b2[c0];
#pragma unroll
        for (int j = 0; j < 4; ++j) acc[j] = bb;
#pragma unroll 2
        for (int k4 = 0; k4 < 16; ++k4) {
            float4 a0[4];
#pragma unroll
            for (int j = 0; j < 4; ++j) a0[j] = *(const float4*)&sAgg[(rg + j) * KP + k4 * 4];
            const float* wp = &sW[k4 * 4 * 64 + c0];
            float4 w0 = *(const float4*)(wp);
            float4 w1 = *(const float4*)(wp + 64);
            float4 w2 = *(const float4*)(wp + 128);
            float4 w3 = *(const float4*)(wp + 192);
#pragma unroll
            for (int j = 0; j < 4; ++j) {
                fma4(acc[j], w0, a0[j].x); fma4(acc[j], w1, a0[j].y);
                fma4(acc[j], w2, a0[j].z); fma4(acc[j], w3, a0[j].w);
            }
        }
    }
#pragma unroll
    for (int j = 0; j < 4; ++j) {
        acc[j].x = fmaxf(acc[j].x, 0.f); acc[j].y = fmaxf(acc[j].y, 0.f);
        acc[j].z = fmaxf(acc[j].z, 0.f); acc[j].w = fmaxf(acc[j].w, 0.f);
        if (rg + j < nrows) stbf4(out + (size_t)(tile + rg + j) * 64 + c0, acc[j]);
    }
    if (tid < 128) sStat[tid] = 0.f;
    __syncthreads();
    float sx = 0, sy = 0, sz = 0, sw = 0, qx = 0, qy = 0, qz = 0, qw = 0;
#pragma unroll
    for (int j = 0; j < 4; ++j) {
        if (rg + j < nrows) {
            sx += acc[j].x; sy += acc[j].y; sz += acc[j].z; sw += acc[j].w;
            qx += acc[j].x * acc[j].x; qy += acc[j].y * acc[j].y;
            qz += acc[j].z * acc[j].z; qw += acc[j].w * acc[j].w;
        }
    }
    atomicAdd(&sStat[c0 + 0], sx); atomicAdd(&sStat[c0 + 1], sy);
    atomicAdd(&sStat[c0 + 2], sz); atomicAdd(&sStat[c0 + 3], sw);
    atomicAdd(&sStat[64 + c0 + 0], qx); atomicAdd(&sStat[64 + c0 + 1], qy);
    atomicAdd(&sStat[64 + c0 + 2], qz); atomicAdd(&sStat[64 + c0 + 3], qw);
    __syncthreads();
    if (tid < 128) atomicAdd(&gstats[tid], sStat[tid]);
}

// ---------------- skinny fp32 GEMM, templated bf16 in/out ----------------

template<int K, bool BIAS, bool RELU, bool STATS, bool ROWSCALE, bool BNIN, bool DUAL,
         bool INBF, bool OUTBF>
__global__ __launch_bounds__(256) void gemm_k(
    const void* __restrict__ in, const float* __restrict__ W, const float* __restrict__ Wb,
    const float* __restrict__ bias, const float* __restrict__ bias2,
    void* __restrict__ out, void* __restrict__ out2, int rows,
    float* __restrict__ gstats, float* __restrict__ gstats2,
    const float* __restrict__ attn, const float* __restrict__ noise,
    const float* __restrict__ bnstats, const float* __restrict__ gamma,
    const float* __restrict__ beta)
{
    constexpr int RPT = (K == 128) ? 2 : 4;
    constexpr int TR  = 16 * RPT;
    constexpr int KP  = K + 4;
    constexpr int SS  = DUAL ? 256 : 128;
    __shared__ float sW[K * 64];
    __shared__ float sWb[DUAL ? K * 64 : 4];
    __shared__ float sIn[TR * KP];
    __shared__ float sStat[STATS ? SS : 4];
    __shared__ float sA[BNIN ? 64 : 4];
    __shared__ float sD[BNIN ? 64 : 4];

    const int tid = threadIdx.x;
    for (int i = tid; i < K * 16; i += 256) ((float4*)sW)[i] = ((const float4*)W)[i];
    if (DUAL)
        for (int i = tid; i < K * 16; i += 256) ((float4*)sWb)[i] = ((const float4*)Wb)[i];
    if (BNIN && tid < 64) {
        float m   = bnstats[tid] * (1.f / NN);
        float v   = bnstats[64 + tid] * (1.f / NN) - m * m;
        float a   = rsqrtf(v + 1e-5f) * gamma[tid];
        sA[tid] = a;
        sD[tid] = beta[tid] - m * a;
    }

    int rg = (tid >> 4) * RPT;
    int c0 = (tid & 15) << 2;
    float4 bb  = make_float4(0.f, 0.f, 0.f, 0.f);
    float4 bb2 = make_float4(0.f, 0.f, 0.f, 0.f);
    if (BIAS) bb = *(const float4*)&bias[c0];
    if (BIAS && DUAL) bb2 = *(const float4*)&bias2[c0];

    for (int tile = blockIdx.x * TR; tile < rows; tile += gridDim.x * TR) {
        __syncthreads();
        int nrows = min(TR, rows - tile);
        const float4* igf = INBF ? nullptr : (const float4*)((const float*)in + (size_t)tile * K);
        const u16*    igb = INBF ? ((const u16*)in + (size_t)tile * K) : nullptr;
        const float4* ng  = ROWSCALE ? (const float4*)(noise + (size_t)tile * K) : nullptr;
        for (int i = tid; i < nrows * (K / 4); i += 256) {
            int rr = i / (K / 4), kk = (i - rr * (K / 4)) * 4;
            float4 t = INBF ? ldbf4(igb + i * 4) : igf[i];
            if (BNIN) {
                t.x = fmaf(sA[kk + 0], t.x, sD[kk + 0]);
                t.y = fmaf(sA[kk + 1], t.y, sD[kk + 1]);
                t.z = fmaf(sA[kk + 2], t.z, sD[kk + 2]);
                t.w = fmaf(sA[kk + 3], t.w, sD[kk + 3]);
            }
            if (ROWSCALE) {
                float4 nv = ng[i];
                float at = attn[tile + rr];
                t.x = fmaf(at, t.x, nv.x); t.y = fmaf(at, t.y, nv.y);
                t.z = fmaf(at, t.z, nv.z); t.w = fmaf(at, t.w, nv.w);
            }
            *(float4*)&sIn[rr * KP + kk] = t;
        }
        __syncthreads();

        float4 acc[RPT];
        float4 acc2[DUAL ? RPT : 1];
#pragma unroll
        for (int j = 0; j < RPT; ++j) acc[j] = bb;
        if (DUAL) {
#pragma unroll
            for (int j = 0; j < RPT; ++j) acc2[j] = bb2;
        }
#pragma unroll 2
        for (int k4 = 0; k4 < K / 4; ++k4) {
            float4 av[RPT];
#pragma unroll
            for (int j = 0; j < RPT; ++j)
                av[j] = *(const float4*)&sIn[(rg + j) * KP + k4 * 4];
            const float* wp = &sW[k4 * 4 * 64 + c0];
            float4 w0 = *(const float4*)(wp);
            float4 w1 = *(const float4*)(wp + 64);
            float4 w2 = *(const float4*)(wp + 128);
            float4 w3 = *(const float4*)(wp + 192);
#pragma unroll
            for (int j = 0; j < RPT; ++j) {
                fma4(acc[j], w0, av[j].x); fma4(acc[j], w1, av[j].y);
                fma4(acc[j], w2, av[j].z); fma4(acc[j], w3, av[j].w);
            }
            if (DUAL) {
                const float* wq = &sWb[k4 * 4 * 64 + c0];
                float4 u0 = *(const float4*)(wq);
                float4 u1 = *(const float4*)(wq + 64);
                float4 u2 = *(const float4*)(wq + 128);
                float4 u3 = *(const float4*)(wq + 192);
#pragma unroll
                for (int j = 0; j < RPT; ++j) {
                    fma4(acc2[j], u0, av[j].x); fma4(acc2[j], u1, av[j].y);
                    fma4(acc2[j], u2, av[j].z); fma4(acc2[j], u3, av[j].w);
                }
            }
        }
        if (RELU) {
#pragma unroll
            for (int j = 0; j < RPT; ++j) {
                acc[j].x = fmaxf(acc[j].x, 0.f); acc[j].y = fmaxf(acc[j].y, 0.f);
                acc[j].z = fmaxf(acc[j].z, 0.f); acc[j].w = fmaxf(acc[j].w, 0.f);
                if (DUAL) {
                    acc2[j].x = fmaxf(acc2[j].x, 0.f); acc2[j].y = fmaxf(acc2[j].y, 0.f);
                    acc2[j].z = fmaxf(acc2[j].z, 0.f); acc2[j].w = fmaxf(acc2[j].w, 0.f);
                }
            }
        }
#pragma unroll
        for (int j = 0; j < RPT; ++j) {
            int r = rg + j;
            if (r < nrows) {
                if (OUTBF) stbf4((u16*)out + (size_t)(tile + r) * 64 + c0, acc[j]);
                else *(float4*)((float*)out + (size_t)(tile + r) * 64 + c0) = acc[j];
                if (DUAL) {
                    if (OUTBF) stbf4((u16*)out2 + (size_t)(tile + r) * 64 + c0, acc2[j]);
                    else *(float4*)((float*)out2 + (size_t)(tile + r) * 64 + c0) = acc2[j];
                }
            }
        }
        if (STATS) {
            if (tid < SS) sStat[tid] = 0.f;
            __syncthreads();
            float sx = 0, sy = 0, sz = 0, sw = 0, qx = 0, qy = 0, qz = 0, qw = 0;
            float sx2 = 0, sy2 = 0, sz2 = 0, sw2 = 0, qx2 = 0, qy2 = 0, qz2 = 0, qw2 = 0;
#pragma unroll
            for (int j = 0; j < RPT; ++j) {
                if (rg + j < nrows) {
                    sx += acc[j].x; sy += acc[j].y; sz += acc[j].z; sw += acc[j].w;
                    qx += acc[j].x * acc[j].x; qy += acc[j].y * acc[j].y;
                    qz += acc[j].z * acc[j].z; qw += acc[j].w * acc[j].w;
                    if (DUAL) {
                        sx2 += acc2[j].x; sy2 += acc2[j].y; sz2 += acc2[j].z; sw2 += acc2[j].w;
                        qx2 += acc2[j].x * acc2[j].x; qy2 += acc2[j].y * acc2[j].y;
                        qz2 += acc2[j].z * acc2[j].z; qw2 += acc2[j].w * acc2[j].w;
                    }
                }
            }
            atomicAdd(&sStat[c0 + 0], sx); atomicAdd(&sStat[c0 + 1], sy);
            atomicAdd(&sStat[c0 + 2], sz); atomicAdd(&sStat[c0 + 3], sw);
            atomicAdd(&sStat[64 + c0 + 0], qx); atomicAdd(&sStat[64 + c0 + 1], qy);
            atomicAdd(&sStat[64 + c0 + 2], qz); atomicAdd(&sStat[64 + c0 + 3], qw);
            if (DUAL) {
                atomicAdd(&sStat[128 + c0 + 0], sx2); atomicAdd(&sStat[128 + c0 + 1], sy2);
                atomicAdd(&sStat[128 + c0 + 2], sz2); atomicAdd(&sStat[128 + c0 + 3], sw2);
                atomicAdd(&sStat[192 + c0 + 0], qx2); atomicAdd(&sStat[192 + c0 + 1], qy2);
                atomicAdd(&sStat[192 + c0 + 2], qz2); atomicAdd(&sStat[192 + c0 + 3], qw2);
            }
            __syncthreads();
            if (tid < 128) atomicAdd(&gstats[tid], sStat[tid]);
            if (DUAL && tid >= 128) atomicAdd(&gstats2[tid - 128], sStat[tid]);
        }
    }
}

// ---------------- paired batchnorm apply: bf16 inputs (node heads) ----------------

__global__ void bn_apply2b_k(const u16* __restrict__ in1, const u16* __restrict__ in2,
                             float* __restrict__ out1, float* __restrict__ out2, int rows,
                             const float* __restrict__ st1, const float* __restrict__ st2,
                             const float* __restrict__ g1, const float* __restrict__ b1,
                             const float* __restrict__ g2, const float* __restrict__ b2) {
    int n = rows * 64;
    float invr = 1.f / (float)rows;
    for (int i = blockIdx.x * blockDim.x + threadIdx.x; i < n; i += gridDim.x * blockDim.x) {
        int c = i & 63;
        float m1 = st1[c] * invr;
        float v1 = st1[64 + c] * invr - m1 * m1;
        out1[i] = (bf2f(in1[i]) - m1) * rsqrtf(v1 + 1e-5f) * g1[c] + b1[c];
        float m2 = st2[c] * invr;
        float v2 = st2[64 + c] * invr - m2 * m2;
        out2[i] = (bf2f(in2[i]) - m2) * rsqrtf(v2 + 1e-5f) * g2[c] + b2[c];
    }
}

// ---------------- paired batchnorm apply: fp32 inputs (graph heads) ----------------

__global__ void bn_apply2_k(const float* __restrict__ in1, const float* __restrict__ in2,
                            float* __restrict__ out1, float* __restrict__ out2, int rows,
                            const float* __restrict__ st1, const float* __restrict__ st2,
                            const float* __restrict__ g1, const float* __restrict__ b1,
                            const float* __restrict__ g2, const float* __restrict__ b2) {
    int n = rows * 64;
    float invr = 1.f / (float)rows;
    for (int i = blockIdx.x * blockDim.x + threadIdx.x; i < n; i += gridDim.x * blockDim.x) {
        int c = i & 63;
        float m1 = st1[c] * invr;
        float v1 = st1[64 + c] * invr - m1 * m1;
        out1[i] = (in1[i] - m1) * rsqrtf(v1 + 1e-5f) * g1[c] + b1[c];
        float m2 = st2[c] * invr;
        float v2 = st2[64 + c] * invr - m2 * m2;
        out2[i] = (in2[i] - m2) * rsqrtf(v2 + 1e-5f) * g2[c] + b2[c];
    }
}

// ---------------- attention on z (bf16) directly; 512 threads, 8 scan groups ----------------

__global__ __launch_bounds__(512) void attn3_k(
    const u16* __restrict__ z, const int* __restrict__ segst,
    const float* __restrict__ bnst, const float* __restrict__ gam, const float* __restrict__ bet,
    const float* __restrict__ Wq, const float* __restrict__ Wk, const float* __restrict__ Wv,
    const float* __restrict__ Wih, const float* __restrict__ Whh,
    const float* __restrict__ bih, const float* __restrict__ bhh,
    float* __restrict__ attn, float* __restrict__ slots_out)
{
    int g = blockIdx.x, tid = threadIdx.x, w = tid >> 6, lane = tid & 63;
    __shared__ float ssl[64], sq[64], swr[64], sm[64], supd[64], sred[512], ssum[8];
    __shared__ float aL[64], dL[64];
    __shared__ float sgi[192], sgh[192];
    __shared__ float sc, sinv;

    int s0 = segst[g], s1 = segst[g + 1];
    if (tid < 64) {
        float m = bnst[tid] * (1.f / NN);
        float v = bnst[64 + tid] * (1.f / NN) - m * m;
        float a = rsqrtf(v + 1e-5f) * gam[tid];
        aL[tid] = a;
        dL[tid] = bet[tid] - m * a;
    }
    __syncthreads();

    // mean init: slots = a o mean(z) + d   (8 row-groups)
    {
        float macc = 0.f;
        for (int n = s0 + w; n < s1; n += 8) macc += bf2f(z[(size_t)n * 64 + lane]);
        sred[tid] = macc;
        __syncthreads();
        if (tid < 64) {
            float s = 0.f;
#pragma unroll
            for (int k = 0; k < 8; ++k) s += sred[tid + 64 * k];
            ssl[tid] = fmaf(aL[tid], s / (float)max(s1 - s0, 1), dL[tid]);
        }
        __syncthreads();
    }

    for (int it = 0; it < 2; ++it) {
        // q = slots @ Wq  (8 groups x 8 k-terms)
        {
            float p = 0.f;
#pragma unroll
            for (int kk = 0; kk < 8; ++kk) p += ssl[w * 8 + kk] * Wq[(w * 8 + kk) * 64 + lane];
            sred[tid] = p;
        }
        __syncthreads();
        if (tid < 64) {
            float s = 0.f;
#pragma unroll
            for (int k = 0; k < 8; ++k) s += sred[tid + 64 * k];
            sq[tid] = s;
        }
        __syncthreads();
        // wraw[j] = sum_i Wk[j][i] * q[i]
        {
            float p = 0.f;
#pragma unroll
            for (int kk = 0; kk < 8; ++kk) p += Wk[lane * 64 + w * 8 + kk] * sq[w * 8 + kk];
            sred[tid] = p;
        }
        __syncthreads();
        if (tid < 64) {
            float s = 0.f;
#pragma unroll
            for (int k = 0; k < 8; ++k) s += sred[tid + 64 * k];
            swr[tid] = s;
        }
        __syncthreads();
        if (tid < 64) {
            float pr = dL[tid] * swr[tid];
            pr += __shfl_xor(pr, 1);  pr += __shfl_xor(pr, 2);  pr += __shfl_xor(pr, 4);
            pr += __shfl_xor(pr, 8);  pr += __shfl_xor(pr, 16); pr += __shfl_xor(pr, 32);
            if (tid == 0) sc = pr * 0.125f;
            swr[tid] = aL[tid] * swr[tid] * 0.125f;
        }
        __syncthreads();
        float wl = swr[lane], cc = sc;

        // fused scan: e = exp(z.w' + c); attn = e; s += e; u += e*z   (8 row-groups)
        float s = 0.f, u = 0.f;
        for (int n = s0 + w; n < s1; n += 8) {
            float zl = bf2f(z[(size_t)n * 64 + lane]);
            float l = zl * wl;
            l += __shfl_xor(l, 1);  l += __shfl_xor(l, 2);  l += __shfl_xor(l, 4);
            l += __shfl_xor(l, 8);  l += __shfl_xor(l, 16); l += __shfl_xor(l, 32);
            float e = expf(l + cc);
            if (lane == 0) attn[n] = e;
            s += e;
            u = fmaf(e, zl, u);
        }
        sred[tid] = u;
        if (lane == 0) ssum[w] = s;
        __syncthreads();
        if (tid < 64) {
            float stot = ssum[0] + ssum[1] + ssum[2] + ssum[3]
                       + ssum[4] + ssum[5] + ssum[6] + ssum[7] + 1e-9f;
            if (tid == 0) sinv = 1.f / stot;
            float uu = 0.f;
#pragma unroll
            for (int k = 0; k < 8; ++k) uu += sred[tid + 64 * k];
            sm[tid] = fmaf(aL[tid], uu / stot, dL[tid]);
        }
        __syncthreads();
        // updates = m @ Wv
        {
            float p = 0.f;
#pragma unroll
            for (int kk = 0; kk < 8; ++kk) p += sm[w * 8 + kk] * Wv[(w * 8 + kk) * 64 + lane];
            sred[tid] = p;
        }
        __syncthreads();
        if (tid < 64) {
            float s2 = 0.f;
#pragma unroll
            for (int k = 0; k < 8; ++k) s2 += sred[tid + 64 * k];
            supd[tid] = s2;
        }
        __syncthreads();

        if (it == 1) {
            float inv = sinv;
            for (int n = s0 + tid; n < s1; n += 512) attn[n] *= inv;
        }

        // GRU
        if (tid < 192) {
            float a = bih[tid], b = bhh[tid];
            const float* wi = &Wih[tid * 64];
            const float* wh = &Whh[tid * 64];
#pragma unroll 8
            for (int j = 0; j < 64; ++j) { a += supd[j] * wi[j]; b += ssl[j] * wh[j]; }
            sgi[tid] = a; sgh[tid] = b;
        }
        __syncthreads();
        if (tid < 64) {
            float r  = 1.f / (1.f + expf(-(sgi[tid] + sgh[tid])));
            float zz = 1.f / (1.f + expf(-(sgi[64 + tid] + sgh[64 + tid])));
            float nn = tanhf(sgi[128 + tid] + r * sgh[128 + tid]);
            float ns = (1.f - zz) * nn + zz * ssl[tid];
            ssl[tid] = ns;
            if (it == 1) slots_out[g * 64 + tid] = ns;
        }
        __syncthreads();
    }
}

// ---------------- host side ----------------

extern "C" void kernel_launch(void* const* d_in, const int* in_sizes, int n_in,
                              void* d_out, int out_size, void* d_ws, size_t ws_size,
                              hipStream_t stream) {
    (void)in_sizes; (void)n_in; (void)out_size; (void)ws_size;

    const float* x      = (const float*)d_in[0];
    const int*   ei     = (const int*)d_in[1];
    const int*   srcI   = ei;
    const int*   dstI   = ei + EE;
    const int*   batch  = (const int*)d_in[2];
    const float* noise  = (const float*)d_in[3];
    const float* W1_0   = (const float*)d_in[4];
    const float* b1_0   = (const float*)d_in[5];
    const float* W2_0   = (const float*)d_in[6];
    const float* b2_0   = (const float*)d_in[7];
    const float* W1_r   = (const float*)d_in[8];
    const float* b1_r   = (const float*)d_in[9];
    const float* W2_r   = (const float*)d_in[10];
    const float* b2_r   = (const float*)d_in[11];
    const float* bn_g   = (const float*)d_in[12];
    const float* bn_b   = (const float*)d_in[13];
    const float* Wq     = (const float*)d_in[14];
    const float* Wk     = (const float*)d_in[15];
    const float* Wv     = (const float*)d_in[16];
    const float* Wih    = (const float*)d_in[17];
    const float* Whh    = (const float*)d_in[18];
    const float* bih    = (const float*)d_in[19];
    const float* bhh    = (const float*)d_in[20];
    const float* nmW    = (const float*)d_in[21];
    const float* nmb    = (const float*)d_in[22];
    const float* nlW    = (const float*)d_in[23];
    const float* nlb    = (const float*)d_in[24];
    const float* gmW    = (const float*)d_in[25];
    const float* gmb    = (const float*)d_in[26];
    const float* glW    = (const float*)d_in[27];
    const float* glb    = (const float*)d_in[28];
    const float* pj_g   = (const float*)d_in[29];
    const float* pj_b   = (const float*)d_in[30];

    char* w = (char*)d_ws;
    u16*   B0b   = (u16*)w;            w += (size_t)NN * 64 * 2;
    u16*   B1b   = (u16*)w;            w += (size_t)NN * 64 * 2;
    u16*   B2b   = (u16*)w;            w += (size_t)NN * 64 * 2;
    float* slots = (float*)w;          w += GG * 64 * 4;
    float* gpre1 = (float*)w;          w += GG * 64 * 4;
    float* gpre2 = (float*)w;          w += GG * 64 * 4;
    float* attn  = (float*)w;          w += NN * 4;
    float* stats = (float*)w;          w += 7 * 128 * 4;
    int*   segst = (int*)w;            w += (GG + 1) * 4;
    int*   rowst = (int*)w;            w += (NN + 1) * 4;
    int*   cursor= (int*)w;            w += NN * 4;
    int*   bsum  = (int*)w;            w += 64 * 4;
    int*   bofs  = (int*)w;            w += 64 * 4;
    u16*   csr16 = (u16*)w;            w += (size_t)EE * 2;

    float* s0 = stats, *s1 = stats + 128, *s2 = stats + 256, *s3 = stats + 384,
         * s4 = stats + 512, *s5 = stats + 640, *s6 = stats + 768;

    float* outp = (float*)d_out;
    float* out_nmu = outp;
    float* out_nlv = outp + NN * DD;
    float* out_gmu = outp + 2 * NN * DD;
    float* out_glv = outp + 2 * NN * DD + GG * DD;

    constexpr int NB = (NN + 1023) / 1024;       // 49 scan chunks
    constexpr int GE2 = (EE / 2 + 255) / 256;    // 1563 (2 edges/thread)
    constexpr int NT64 = (NN + 63) / 64;         // 782 64-row tiles
    const float* np = nullptr;
    float* zp = nullptr;

#define GK(...) <<<__VA_ARGS__, 0, stream>>>
    // ---------- init + CSR build + segments ----------
    zero_all_k GK((NN + 255) / 256, 256)(cursor, stats);
    hist_k GK(GE2, 256)(dstI, cursor);
    scanA_k GK(NB, 1024)(cursor, rowst, bsum);
    scanB_k GK(1, 64)(bsum, bofs, NB);
    scanC_k GK((NN + 255) / 256, 256)(rowst, bofs, cursor);
    fill_k GK(GE2, 256)(srcI, dstI, cursor, csr16);
    seg_bounds_k GK(3, 256)(batch, segst);

    // ---------- GIN layer 0: x@W1 (K=128, fp32 in -> bf16 out), fused gather+W2 ----------
    gemm_k<128,false,false,false,false,false,false,false,true> GK(1563, 256)
        (x, W1_0, np, np, np, B0b, zp, NN, zp, zp, np, np, np, np, np);
    agg_gemm_k GK(NT64, 256)(B0b, rowst, csr16, b1_0, W2_0, b2_0, B1b, s0);

    // ---------- GIN layers 1,2 (fully fused; bf16 in/out; 64-row tiles) ----------
    fused_layer_k GK(NT64, 256)(B1b, rowst, csr16, s0, bn_g + 0, bn_b + 0,
                                W1_r, b1_r, W2_r, b2_r, B2b, s1);
    fused_layer_k GK(NT64, 256)(B2b, rowst, csr16, s1, bn_g + 64, bn_b + 64,
                                W1_r + DD * DD, b1_r + DD, W2_r + DD * DD, b2_r + DD, B0b, s2);
    // B0b = z2 (pre-BN, relu'd, bf16); BN2 affine (s2, bn[2]) fused into all consumers.

    // ---------- summary maker: attention directly on z2 (512 threads) ----------
    attn3_k GK(GG, 512)(B0b, segst, s2, bn_g + 128, bn_b + 128,
                        Wq, Wk, Wv, Wih, Whh, bih, bhh, attn, slots);

    // ---------- node heads (noisy fused; bf16 outs into dead B1b/B2b) ----------
    gemm_k<64,true,true,true,true,true,true,true,true> GK(782, 256)
        (B0b, nmW, nlW, nmb, nlb, B1b, B2b, NN, s3, s4, attn, noise, s2, bn_g + 128, bn_b + 128);
    bn_apply2b_k GK(2048, 256)(B1b, B2b, out_nmu, out_nlv, NN, s3, s4,
                               pj_g + 0, pj_b + 0, pj_g + 64, pj_b + 64);

    // ---------- graph heads ----------
    gemm_k<64,true,true,true,false,false,true,false,false> GK(8, 256)
        (slots, gmW, glW, gmb, glb, gpre1, gpre2, GG, s5, s6, np, np, np, np, np);
    bn_apply2_k GK(128, 256)(gpre1, gpre2, out_gmu, out_glv, GG, s5, s6,
                             pj_g + 128, pj_b + 128, pj_g + 192, pj_b + 192);
#undef GK
}